// Round 4
// baseline (230.567 us; speedup 1.0000x reference)
//
#include <hip/hip_runtime.h>
#include <hip/hip_bf16.h>
#include <cstdint>

#define BATCH 4
#define SEQ   2048
#define DIN   1024
#define DOUT  1024
#define SCALE 0.03125f   // 1/sqrt(1024)

typedef unsigned short u16;
typedef float  f32x4  __attribute__((ext_vector_type(4)));
typedef __bf16 bf16x8 __attribute__((ext_vector_type(8)));

__device__ __forceinline__ u16 f2bf(float f) {
    unsigned u = __float_as_uint(f);
    unsigned r = 0x7fffu + ((u >> 16) & 1u);
    return (u16)((u + r) >> 16);
}

__device__ __forceinline__ f32x4 mfma16(bf16x8 a, bf16x8 b, f32x4 c) {
    return __builtin_amdgcn_mfma_f32_16x16x32_bf16(a, b, c, 0, 0, 0);
}

// async global->LDS, 16B per lane, wave-uniform LDS base
__device__ __forceinline__ void gl_lds16(const u16* g, u16* l) {
    __builtin_amdgcn_global_load_lds(
        (const __attribute__((address_space(1))) unsigned int*)g,
        (__attribute__((address_space(3))) unsigned int*)l, 16, 0, 0);
}

// swizzle for 64B-stride rows: bank bits get row bits 1,2 -> conflict-free
// involution (source bits 7,8 untouched); 16B-granule-preserving (bits 0-3 untouched)
__device__ __forceinline__ int swz2(int p) {
    return p ^ ((((p) >> 7) & 1) << 5) ^ ((((p) >> 8) & 1) << 4);
}

// ---------------- fp32 -> bf16 conversion (8 elems/thread) ----------------
__global__ __launch_bounds__(256) void cvt_bf16(const float* __restrict__ in,
                                                u16* __restrict__ out) {
    size_t i = ((size_t)blockIdx.x * 256 + threadIdx.x) * 8;
    f32x4 a = *(const f32x4*)(in + i);
    f32x4 b = *(const f32x4*)(in + i + 4);
    uint4 o;
    o.x = (unsigned)f2bf(a[0]) | ((unsigned)f2bf(a[1]) << 16);
    o.y = (unsigned)f2bf(a[2]) | ((unsigned)f2bf(a[3]) << 16);
    o.z = (unsigned)f2bf(b[0]) | ((unsigned)f2bf(b[1]) << 16);
    o.w = (unsigned)f2bf(b[2]) | ((unsigned)f2bf(b[3]) << 16);
    *(uint4*)(out + i) = o;
}

// ======================================================================
// 128x256 tile, BK=64 (2 kk-phases), 8 waves (2M x 4N), per-wave 64x64.
// LDS 96KB: A [2buf][2kk] 8KB units (128r x 32e); B [2buf][2kk] 16KB units
// (256r x 32e). Uniform phase: 8 ds_read + 3 gl_lds + vmcnt(6) + bar +
// 16 MFMA (setprio) + bar. 2-phase load lead; inverse-swizzled global src.
// ======================================================================
__device__ __forceinline__ void stA(const u16* __restrict__ g, int ld,
                                    u16* unit, int tid) {
    int o = tid * 16;            // 512 threads x 16B = 8KB
    int p = swz2(o);
    gl_lds16(g + (size_t)(p >> 6) * ld + ((p & 63) >> 1), unit + (tid >> 6) * 512);
}

__device__ __forceinline__ void stB(const u16* __restrict__ g, int ld,
                                    u16* unit, int tid) {
#pragma unroll
    for (int i = 0; i < 2; i++) {
        int o = i * 8192 + tid * 16;   // 16KB
        int p = swz2(o);
        gl_lds16(g + (size_t)(p >> 6) * ld + ((p & 63) >> 1),
                 unit + i * 4096 + (tid >> 6) * 512);
    }
}

__device__ __forceinline__ void ldfrag(const char* Ab, const char* Bb,
                                       int wm, int wn, int l15, int l4c,
                                       bf16x8 a[4], bf16x8 b[4]) {
#pragma unroll
    for (int mi = 0; mi < 4; mi++)
        a[mi] = *(const bf16x8*)(Ab + swz2((wm * 64 + mi * 16 + l15) * 64 + l4c));
#pragma unroll
    for (int ni = 0; ni < 4; ni++)
        b[ni] = *(const bf16x8*)(Bb + swz2((wn * 64 + ni * 16 + l15) * 64 + l4c));
}

__device__ __forceinline__ void do_mfma(bf16x8 a[4], bf16x8 b[4], f32x4 acc[4][4]) {
    __builtin_amdgcn_s_setprio(1);
#pragma unroll
    for (int mi = 0; mi < 4; mi++)
#pragma unroll
        for (int ni = 0; ni < 4; ni++)
            acc[mi][ni] = mfma16(a[mi], b[ni], acc[mi][ni]);
    __builtin_amdgcn_s_setprio(0);
}

#define GEMM2_BODY(Ag, Bg, LD, NKT)                                              \
    u16 *A_[2][2], *B_[2][2];                                                    \
    _Pragma("unroll") for (int bf = 0; bf < 2; bf++)                             \
        _Pragma("unroll") for (int kk = 0; kk < 2; kk++) {                       \
            A_[bf][kk] = lds + bf * 8192 + kk * 4096;                            \
            B_[bf][kk] = lds + 16384 + bf * 16384 + kk * 8192;                   \
        }                                                                        \
    f32x4 acc[4][4] = {};                                                        \
    stA(Ag + 0,  LD, A_[0][0], tid); stB(Bg + 0,  LD, B_[0][0], tid);            \
    stA(Ag + 32, LD, A_[0][1], tid); stB(Bg + 32, LD, B_[0][1], tid);            \
    stA(Ag + 64, LD, A_[1][0], tid); stB(Bg + 64, LD, B_[1][0], tid);            \
    asm volatile("s_waitcnt vmcnt(6)" ::: "memory");                             \
    asm volatile("s_barrier" ::: "memory");                                      \
    for (int t = 0; t < (NKT); t++) {                                            \
        const int cur = t & 1, nxt = cur ^ 1;                                    \
        const int t1 = (t + 1 < (NKT)) ? t + 1 : (NKT)-1;                        \
        const int t2 = (t + 2 < (NKT)) ? t + 2 : (NKT)-1;                        \
        bf16x8 a[4], b[4];                                                       \
        ldfrag((const char*)A_[cur][0], (const char*)B_[cur][0],                 \
               wm, wn, l15, l4c, a, b);                                          \
        stA(Ag + t1 * 64 + 32, LD, A_[nxt][1], tid);                             \
        stB(Bg + t1 * 64 + 32, LD, B_[nxt][1], tid);                             \
        asm volatile("s_waitcnt vmcnt(6)" ::: "memory");                         \
        asm volatile("s_barrier" ::: "memory");                                  \
        do_mfma(a, b, acc);                                                      \
        asm volatile("s_barrier" ::: "memory");                                  \
        ldfrag((const char*)A_[cur][1], (const char*)B_[cur][1],                 \
               wm, wn, l15, l4c, a, b);                                          \
        stA(Ag + t2 * 64, LD, A_[cur][0], tid);                                  \
        stB(Bg + t2 * 64, LD, B_[cur][0], tid);                                  \
        asm volatile("s_waitcnt vmcnt(6)" ::: "memory");                         \
        asm volatile("s_barrier" ::: "memory");                                  \
        do_mfma(a, b, acc);                                                      \
        asm volatile("s_barrier" ::: "memory");                                  \
    }                                                                            \
    asm volatile("s_waitcnt vmcnt(0)" ::: "memory");

// ---- fused QKV: C[8192,3072] = X * Wcat^T, bf16 out; grid 768 = 3x256 -----
__global__ __launch_bounds__(512) void qkv2(const u16* __restrict__ xb,
                                            const u16* __restrict__ wb,
                                            u16* __restrict__ qkv) {
    extern __shared__ __align__(16) u16 lds[];
    const int bid = blockIdx.x;
    const int wg = (bid & 7) * 96 + (bid >> 3);   // bijective XCD swizzle (768%8==0)
    const int mt = wg & 63, nt = wg >> 6;         // mt fastest: W panel stays hot
    const int m0 = mt * 128, n0 = nt * 256;
    const int tid = threadIdx.x, lane = tid & 63;
    const int wm = (tid >> 6) >> 2, wn = (tid >> 6) & 3;
    const int l15 = lane & 15, l4 = lane >> 4, l4c = l4 * 16;
    const u16* Ag = xb + (size_t)m0 * DIN;
    const u16* Bg = wb + (size_t)n0 * DIN;

    GEMM2_BODY(Ag, Bg, DIN, 16)

    const int wsel = n0 >> 10, c0 = n0 & 1023;
    u16* Op = qkv + (size_t)wsel * ((size_t)BATCH * SEQ * DOUT);
#pragma unroll
    for (int mi = 0; mi < 4; mi++)
#pragma unroll
        for (int ni = 0; ni < 4; ni++)
#pragma unroll
            for (int rr = 0; rr < 4; rr++) {
                int row = m0 + wm * 64 + mi * 16 + l4 * 4 + rr;
                int col = c0 + wn * 64 + ni * 16 + l15;
                Op[(size_t)row * DOUT + col] = f2bf(acc[mi][ni][rr]);
            }
}

// ---- PV: O = P * V^T-layout, fp32 out, causal nkt, longest-first ----------
__global__ __launch_bounds__(512) void pv2(const u16* __restrict__ pg,
                                           const u16* __restrict__ vtg,
                                           float* __restrict__ og) {
    extern __shared__ __align__(16) u16 lds[];
    const int mt = 15 - (int)blockIdx.x;          // longest-first
    const int n0 = blockIdx.y * 256;
    const int bb = blockIdx.z;
    const int m0 = mt * 128;
    const int nkt = (mt + 1) * 2;                 // causal K bound, >=2
    const int tid = threadIdx.x, lane = tid & 63;
    const int wm = (tid >> 6) >> 2, wn = (tid >> 6) & 3;
    const int l15 = lane & 15, l4 = lane >> 4, l4c = l4 * 16;
    const u16* Ag = pg + (size_t)bb * SEQ * SEQ + (size_t)m0 * SEQ;
    const u16* Bg = vtg + (size_t)bb * DOUT * SEQ + (size_t)n0 * SEQ;

    GEMM2_BODY(Ag, Bg, SEQ, nkt)

    float* Oq = og + (size_t)bb * SEQ * DOUT;
#pragma unroll
    for (int mi = 0; mi < 4; mi++)
#pragma unroll
        for (int ni = 0; ni < 4; ni++)
#pragma unroll
            for (int rr = 0; rr < 4; rr++) {
                int row = m0 + wm * 64 + mi * 16 + l4 * 4 + rr;
                int col = n0 + wn * 64 + ni * 16 + l15;
                Oq[(size_t)row * DOUT + col] = acc[mi][ni][rr];
            }
}

// ---------------- m97-style pieces for qk (unchanged) ----------------------
__device__ __forceinline__ void stage_tile(const u16* __restrict__ g, int ldg,
                                           u16* lds, int tid) {
    const int wv = tid >> 6;
#pragma unroll
    for (int i = 0; i < 4; i++) {
        int e = (i * 256 + tid) * 8;
        int r = e >> 6, c = e & 63;
        gl_lds16(g + (size_t)r * ldg + c, lds + (size_t)(i * 256 + wv * 64) * 8);
    }
}

__device__ __forceinline__ void kstep(const u16* As, const u16* Bs,
                                      int wr, int wc, int l15, int l4,
                                      f32x4 acc[4][4]) {
#pragma unroll
    for (int kk = 0; kk < 2; kk++) {
        bf16x8 af[4], bfr[4];
#pragma unroll
        for (int mi = 0; mi < 4; mi++)
            af[mi] = *(const bf16x8*)&As[(wr + mi * 16 + l15) * 64 + kk * 32 + l4 * 8];
#pragma unroll
        for (int ni = 0; ni < 4; ni++)
            bfr[ni] = *(const bf16x8*)&Bs[(wc + ni * 16 + l15) * 64 + kk * 32 + l4 * 8];
#pragma unroll
        for (int mi = 0; mi < 4; mi++)
#pragma unroll
            for (int ni = 0; ni < 4; ni++)
                acc[mi][ni] = mfma16(af[mi], bfr[ni], acc[mi][ni]);
    }
}

// ---------------- V transpose: v[b][s][d] -> vt[b][d][s] -------------------
__global__ __launch_bounds__(256) void vtrans(const u16* __restrict__ v,
                                              u16* __restrict__ vt) {
    __shared__ __align__(16) u16 t[64][80];
    const int s0 = blockIdx.x * 64, d0 = blockIdx.y * 64;
    const size_t bo = (size_t)blockIdx.z * SEQ * DOUT;
    const int tid = threadIdx.x;
#pragma unroll
    for (int i = 0; i < 2; i++) {
        int e = (tid + i * 256) * 8;
        int r = e >> 6, c = e & 63;
        *(uint4*)&t[r][c] = *(const uint4*)&v[bo + (size_t)(s0 + r) * DOUT + d0 + c];
    }
    __syncthreads();
#pragma unroll
    for (int i = 0; i < 2; i++) {
        int e = (tid + i * 256) * 8;
        int rd = e >> 6, cs = e & 63;
        u16 tmp[8];
#pragma unroll
        for (int j = 0; j < 8; j++) tmp[j] = t[cs + j][rd];
        uint4 o;
        o.x = (unsigned)tmp[0] | ((unsigned)tmp[1] << 16);
        o.y = (unsigned)tmp[2] | ((unsigned)tmp[3] << 16);
        o.z = (unsigned)tmp[4] | ((unsigned)tmp[5] << 16);
        o.w = (unsigned)tmp[6] | ((unsigned)tmp[7] << 16);
        *(uint4*)&vt[(size_t)blockIdx.z * DOUT * SEQ + (size_t)(d0 + rd) * SEQ + s0 + cs] = o;
    }
}

// ---------------- QK^T: S[b][q][k] (bf16, scaled+masked), causal skip ------
__global__ __launch_bounds__(256) void qk_gemm(const u16* __restrict__ qg,
                                               const u16* __restrict__ kg,
                                               u16* __restrict__ sg) {
    const int mt = blockIdx.x, nt = blockIdx.y, b = blockIdx.z;
    if (nt > mt) return;
    __shared__ __align__(16) u16 As[128 * 64];
    __shared__ __align__(16) u16 Bs[128 * 64];
    const size_t bo = (size_t)b * SEQ * DOUT;
    const size_t so = (size_t)b * SEQ * SEQ;
    const int tid = threadIdx.x, lane = tid & 63, wv = tid >> 6;
    const int wr = (wv >> 1) * 64, wc = (wv & 1) * 64;
    const int l15 = lane & 15, l4 = lane >> 4;
    const int m0 = mt * 128, n0 = nt * 128;
    f32x4 acc[4][4] = {};

    for (int k0 = 0; k0 < DIN; k0 += 64) {
        __syncthreads();
        stage_tile(qg + bo + (size_t)m0 * DOUT + k0, DOUT, As, tid);
        stage_tile(kg + bo + (size_t)n0 * DOUT + k0, DOUT, Bs, tid);
        __syncthreads();
        kstep(As, Bs, wr, wc, l15, l4, acc);
    }
#pragma unroll
    for (int mi = 0; mi < 4; mi++)
#pragma unroll
        for (int rr = 0; rr < 4; rr++) {
            int q = m0 + wr + mi * 16 + l4 * 4 + rr;
#pragma unroll
            for (int ni = 0; ni < 4; ni++) {
                int kcol = n0 + wc + ni * 16 + l15;
                u16 val = (kcol <= q) ? f2bf(acc[mi][ni][rr] * SCALE) : (u16)0xFF80;
                sg[so + (size_t)q * SEQ + kcol] = val;
            }
        }
}

// ---------------- row softmax in place: one wave per row -------------------
__global__ __launch_bounds__(256) void softmax_rows(u16* __restrict__ sg) {
    const int row = blockIdx.x * 4 + (threadIdx.x >> 6);
    const int lane = threadIdx.x & 63;
    const int b = row >> 11, q = row & 2047;
    u16* srow = sg + (size_t)b * SEQ * SEQ + (size_t)q * SEQ;
    const int kend = ((q >> 7) + 1) << 7;
    float v[4][8];
    float m = -__builtin_inff();
#pragma unroll
    for (int c = 0; c < 4; c++) {
        int k = c * 512 + lane * 8;
        if (k < kend) {
            uint4 x = *(const uint4*)&srow[k];
            unsigned w0 = x.x, w1 = x.y, w2 = x.z, w3 = x.w;
            v[c][0] = __uint_as_float(w0 << 16); v[c][1] = __uint_as_float(w0 & 0xffff0000u);
            v[c][2] = __uint_as_float(w1 << 16); v[c][3] = __uint_as_float(w1 & 0xffff0000u);
            v[c][4] = __uint_as_float(w2 << 16); v[c][5] = __uint_as_float(w2 & 0xffff0000u);
            v[c][6] = __uint_as_float(w3 << 16); v[c][7] = __uint_as_float(w3 & 0xffff0000u);
        } else {
#pragma unroll
            for (int j = 0; j < 8; j++) v[c][j] = -__builtin_inff();
        }
#pragma unroll
        for (int j = 0; j < 8; j++) m = fmaxf(m, v[c][j]);
    }
#pragma unroll
    for (int off = 32; off >= 1; off >>= 1) m = fmaxf(m, __shfl_xor(m, off));
    float s = 0.f;
#pragma unroll
    for (int c = 0; c < 4; c++)
#pragma unroll
        for (int j = 0; j < 8; j++) { v[c][j] = __expf(v[c][j] - m); s += v[c][j]; }
#pragma unroll
    for (int off = 32; off >= 1; off >>= 1) s += __shfl_xor(s, off);
    float inv = 1.f / s;
#pragma unroll
    for (int c = 0; c < 4; c++) {
        int k = c * 512 + lane * 8;
        if (k < kend) {
            uint4 o;
            o.x = (unsigned)f2bf(v[c][0] * inv) | ((unsigned)f2bf(v[c][1] * inv) << 16);
            o.y = (unsigned)f2bf(v[c][2] * inv) | ((unsigned)f2bf(v[c][3] * inv) << 16);
            o.z = (unsigned)f2bf(v[c][4] * inv) | ((unsigned)f2bf(v[c][5] * inv) << 16);
            o.w = (unsigned)f2bf(v[c][6] * inv) | ((unsigned)f2bf(v[c][7] * inv) << 16);
            *(uint4*)&srow[k] = o;
        }
    }
}

extern "C" void kernel_launch(void* const* d_in, const int* in_sizes, int n_in,
                              void* d_out, int out_size, void* d_ws, size_t ws_size,
                              hipStream_t stream) {
    const float* x  = (const float*)d_in[0];
    const float* wq = (const float*)d_in[1];
    const float* wk = (const float*)d_in[2];
    const float* wv = (const float*)d_in[3];
    float* out = (float*)d_out;

    const size_t NX  = (size_t)BATCH * SEQ * DIN;  // 8M elems
    const size_t NWT = (size_t)DOUT * DIN;         // 1M elems
    u16* xb  = (u16*)d_ws;            // 16 MB
    u16* wb  = xb + NX;               // 6 MB (wq|wk|wv = Wcat[3072][1024])
    u16* qkv = wb + 3 * NWT;          // 48 MB (q,k,v)
    u16* vt  = qkv + 3 * NX;          // 16 MB
    u16* sb  = vt + NX;               // 33.5 MB scores/probs (bf16, in-place)

    cvt_bf16<<<NX / 8 / 256, 256, 0, stream>>>(x, xb);
    cvt_bf16<<<NWT / 8 / 256, 256, 0, stream>>>(wq, wb);
    cvt_bf16<<<NWT / 8 / 256, 256, 0, stream>>>(wk, wb + NWT);
    cvt_bf16<<<NWT / 8 / 256, 256, 0, stream>>>(wv, wb + 2 * NWT);

    (void)hipFuncSetAttribute((const void*)qkv2,
                              hipFuncAttributeMaxDynamicSharedMemorySize, 98304);
    (void)hipFuncSetAttribute((const void*)pv2,
                              hipFuncAttributeMaxDynamicSharedMemorySize, 98304);

    qkv2<<<dim3(768), dim3(512), 98304, stream>>>(xb, wb, qkv);

    vtrans<<<dim3(SEQ / 64, DOUT / 64, BATCH), 256, 0, stream>>>(qkv + 2 * NX, vt);

    qk_gemm<<<dim3(16, 16, 4), 256, 0, stream>>>(qkv, qkv + NX, sb);

    softmax_rows<<<(BATCH * SEQ) / 4, 256, 0, stream>>>(sb);

    pv2<<<dim3(16, 4, 4), dim3(512), 98304, stream>>>(sb, vt, out);
}

// Round 5
// 194.385 us; speedup vs baseline: 1.1861x; 1.1861x over previous
//
#include <hip/hip_runtime.h>
#include <hip/hip_bf16.h>
#include <cstdint>

#define BATCH 4
#define SEQ   2048
#define DIN   1024
#define DOUT  1024
#define SCALE 0.03125f   // 1/sqrt(1024)

typedef unsigned short u16;
typedef float  f32x4  __attribute__((ext_vector_type(4)));
typedef __bf16 bf16x8 __attribute__((ext_vector_type(8)));

__device__ __forceinline__ u16 f2bf(float f) {
    unsigned u = __float_as_uint(f);
    unsigned r = 0x7fffu + ((u >> 16) & 1u);
    return (u16)((u + r) >> 16);
}

__device__ __forceinline__ f32x4 mfma16(bf16x8 a, bf16x8 b, f32x4 c) {
    return __builtin_amdgcn_mfma_f32_16x16x32_bf16(a, b, c, 0, 0, 0);
}

// async global->LDS, 16B per lane, wave-uniform LDS base
__device__ __forceinline__ void gl_lds16(const u16* g, u16* l) {
    __builtin_amdgcn_global_load_lds(
        (const __attribute__((address_space(1))) unsigned int*)g,
        (__attribute__((address_space(3))) unsigned int*)l, 16, 0, 0);
}

#define BAR    asm volatile("s_barrier" ::: "memory")
#define VMCNT4 asm volatile("s_waitcnt vmcnt(4)" ::: "memory")
#define VMCNT0 asm volatile("s_waitcnt vmcnt(0)" ::: "memory")

// ---------------- fused fp32 -> bf16 conversion (x | wq | wk | wv) ---------
__global__ __launch_bounds__(256) void cvt_all(const float* __restrict__ x,
                                               const float* __restrict__ wq,
                                               const float* __restrict__ wk,
                                               const float* __restrict__ wv,
                                               u16* __restrict__ dst) {
    const size_t NX  = (size_t)BATCH * SEQ * DIN;
    size_t e = ((size_t)blockIdx.x * 256 + threadIdx.x) * 8;
    const float* src;
    size_t off;
    if (e < NX) { src = x; off = e; }
    else {
        size_t r = e - NX;
        int w = (int)(r >> 20);
        src = (w == 0) ? wq : (w == 1) ? wk : wv;
        off = r & ((1u << 20) - 1);
    }
    f32x4 a = *(const f32x4*)(src + off);
    f32x4 b = *(const f32x4*)(src + off + 4);
    uint4 o;
    o.x = (unsigned)f2bf(a[0]) | ((unsigned)f2bf(a[1]) << 16);
    o.y = (unsigned)f2bf(a[2]) | ((unsigned)f2bf(a[3]) << 16);
    o.z = (unsigned)f2bf(b[0]) | ((unsigned)f2bf(b[1]) << 16);
    o.w = (unsigned)f2bf(b[2]) | ((unsigned)f2bf(b[3]) << 16);
    *(uint4*)(dst + e) = o;
}

// ======================================================================
// QKV: C[8192,3072] = X[8192,1024] * Wcat[3072,1024]^T  (m201-faithful)
// 256x256 tile, BK=64, 8 waves (2M x 4N), per-wave 128x64, acc[8][4].
// LDS 128KB: A units [buf][half] 16KB (128r x 64c), B likewise.
// 8 phases / 2 K-tiles; stage 1 half-tile per phase; vmcnt(4) at ph3,ph7.
// Swizzle: byte ^= (row&7)<<4 (read side + inverse on global source).
// Persistent: 256 blocks over 384 tiles.
// ======================================================================
__device__ __forceinline__ void stg_half(const u16* __restrict__ gbase,
                                         u16* unit, int tid) {
#pragma unroll
    for (int i = 0; i < 2; i++) {
        int D = (i * 512 + tid) * 16;          // linear dest byte in unit
        int r = D >> 7, w = D & 127;
        int gcol = (w ^ ((r & 7) << 4)) >> 1;  // inverse swizzle on source
        gl_lds16(gbase + (size_t)r * DIN + gcol,
                 unit + (i * 512 + (tid >> 6) * 64) * 8);
    }
}

__device__ __forceinline__ void rdA(const u16* unit, int mh, int l15, int l4,
                                    int sw, bf16x8 a[4][2]) {
    const char* u = (const char*)unit;
#pragma unroll
    for (int mi = 0; mi < 4; mi++)
#pragma unroll
        for (int kk = 0; kk < 2; kk++)
            a[mi][kk] = *(const bf16x8*)(u + (mh * 64 + mi * 16 + l15) * 128 +
                                         ((kk * 64 + l4 * 16) ^ sw));
}

__device__ __forceinline__ void rdB(const u16* unit, int wn1, int nh, int l15,
                                    int l4, int sw, bf16x8 b[2][2]) {
    const char* u = (const char*)unit;
#pragma unroll
    for (int ni = 0; ni < 2; ni++)
#pragma unroll
        for (int kk = 0; kk < 2; kk++)
            b[ni][kk] = *(const bf16x8*)(u + (wn1 * 64 + nh * 32 + ni * 16 + l15) * 128 +
                                         ((kk * 64 + l4 * 16) ^ sw));
}

#define QUAD(MH, NH)                                                         \
    __builtin_amdgcn_s_setprio(1);                                           \
    _Pragma("unroll") for (int kk = 0; kk < 2; kk++)                         \
    _Pragma("unroll") for (int mi = 0; mi < 4; mi++)                         \
    _Pragma("unroll") for (int ni = 0; ni < 2; ni++)                         \
        acc[(MH)*4 + mi][(NH)*2 + ni] =                                      \
            mfma16(a[mi][kk], bb[NH][ni][kk], acc[(MH)*4 + mi][(NH)*2 + ni]);\
    __builtin_amdgcn_s_setprio(0);

__global__ __launch_bounds__(512) void qkv_gemm256(const u16* __restrict__ xb,
                                                   const u16* __restrict__ wb,
                                                   u16* __restrict__ qkv) {
    extern __shared__ __align__(16) u16 lds[];
    const int tid = threadIdx.x, lane = tid & 63, wid = tid >> 6;
    const int wm = wid >> 2, wn = wid & 3, bh = wn >> 1, wn1 = wn & 1;
    const int l15 = lane & 15, l4 = lane >> 4;
    const int sw = (l15 & 7) << 4;

    // LDS units (u16 offsets; 8192 u16 = 16KB each)
    u16* A00 = lds;              u16* A01 = lds + 8192;    // buf0 halves
    u16* A10 = lds + 16384;      u16* A11 = lds + 24576;   // buf1 halves
    u16* B00 = lds + 32768;      u16* B01 = lds + 40960;
    u16* B10 = lds + 49152;      u16* B11 = lds + 57344;
    u16* Ar0 = lds + wm * 8192;            // A_[0][wm] (read)
    u16* Ar1 = lds + 16384 + wm * 8192;    // A_[1][wm]
    u16* Br0 = lds + 32768 + bh * 8192;    // B_[0][bh]
    u16* Br1 = lds + 49152 + bh * 8192;    // B_[1][bh]

    for (int tile = blockIdx.x; tile < 384; tile += 256) {
        const int wg = (tile & 7) * 48 + (tile >> 3);  // bijective XCD swizzle
        const int mt = wg & 31, nt = wg >> 5;
        const int m0 = mt * 256, n0 = nt * 256;
        const u16* Ag = xb + (size_t)m0 * DIN;
        const u16* Bg = wb + (size_t)n0 * DIN;
        f32x4 acc[8][4] = {};
        bf16x8 a[4][2], bb[2][2][2];

        // prologue: t0{B0,B1,A0,A1}, t1{B0,B1}  (12 loads/thread)
        stg_half(Bg,                          B00, tid);
        stg_half(Bg + (size_t)128 * DIN,      B01, tid);
        stg_half(Ag,                          A00, tid);
        stg_half(Ag + (size_t)128 * DIN,      A01, tid);
        stg_half(Bg + 64,                     B10, tid);
        stg_half(Bg + (size_t)128 * DIN + 64, B11, tid);
        VMCNT4;   // t0 complete; t1 B-halves in flight
        BAR;

        for (int i = 0; i < 8; i++) {
            const int t1k = (2 * i + 1) * 64;
            const int k2 = ((2 * i + 2 < 16) ? 2 * i + 2 : 15) * 64;
            const int k3 = ((2 * i + 3 < 16) ? 2 * i + 3 : 15) * 64;
            // ---- K-tile t0 = 2i (buf0) ----
            // ph0 (mh0,nh0)
            rdA(Ar0, 0, l15, l4, sw, a);
            rdB(Br0, wn1, 0, l15, l4, sw, bb[0]);
            stg_half(Ag + t1k, A10, tid);
            BAR; QUAD(0, 0); BAR;
            // ph1 (mh0,nh1)
            rdB(Br0, wn1, 1, l15, l4, sw, bb[1]);
            stg_half(Ag + (size_t)128 * DIN + t1k, A11, tid);
            BAR; QUAD(0, 1); BAR;
            // ph2 (mh1,nh0)
            rdA(Ar0, 1, l15, l4, sw, a);
            stg_half(Bg + k2, B00, tid);
            BAR; QUAD(1, 0); BAR;
            // ph3 (mh1,nh1)
            stg_half(Bg + (size_t)128 * DIN + k2, B01, tid);
            VMCNT4; BAR; QUAD(1, 1); BAR;
            // ---- K-tile t1 = 2i+1 (buf1) ----
            // ph4
            rdA(Ar1, 0, l15, l4, sw, a);
            rdB(Br1, wn1, 0, l15, l4, sw, bb[0]);
            stg_half(Ag + k2, A00, tid);
            BAR; QUAD(0, 0); BAR;
            // ph5
            rdB(Br1, wn1, 1, l15, l4, sw, bb[1]);
            stg_half(Ag + (size_t)128 * DIN + k2, A01, tid);
            BAR; QUAD(0, 1); BAR;
            // ph6
            rdA(Ar1, 1, l15, l4, sw, a);
            stg_half(Bg + k3, B10, tid);
            BAR; QUAD(1, 0); BAR;
            // ph7
            stg_half(Bg + (size_t)128 * DIN + k3, B11, tid);
            VMCNT4; BAR; QUAD(1, 1); BAR;
        }
        VMCNT0;  // drain tail redundant stages before next tile / exit

        const int wsel = n0 >> 10, c0 = n0 & 1023;
        u16* Op = qkv + (size_t)wsel * ((size_t)BATCH * SEQ * DOUT);
#pragma unroll
        for (int ai = 0; ai < 8; ai++)
#pragma unroll
            for (int bj = 0; bj < 4; bj++)
#pragma unroll
                for (int rr = 0; rr < 4; rr++) {
                    int row = m0 + wm * 128 + ai * 16 + l4 * 4 + rr;
                    int col = c0 + wn * 64 + bj * 16 + l15;
                    Op[(size_t)row * DOUT + col] = f2bf(acc[ai][bj][rr]);
                }
    }
}

// ---------------- m97-style pieces (qk, pv) --------------------------------
__device__ __forceinline__ void stage_tile(const u16* __restrict__ g, int ldg,
                                           u16* lds, int tid) {
    const int wv = tid >> 6;
#pragma unroll
    for (int i = 0; i < 4; i++) {
        int e = (i * 256 + tid) * 8;
        int r = e >> 6, c = e & 63;
        gl_lds16(g + (size_t)r * ldg + c, lds + (size_t)(i * 256 + wv * 64) * 8);
    }
}

__device__ __forceinline__ void kstep(const u16* As, const u16* Bs,
                                      int wr, int wc, int l15, int l4,
                                      f32x4 acc[4][4]) {
#pragma unroll
    for (int kk = 0; kk < 2; kk++) {
        bf16x8 af[4], bfr[4];
#pragma unroll
        for (int mi = 0; mi < 4; mi++)
            af[mi] = *(const bf16x8*)&As[(wr + mi * 16 + l15) * 64 + kk * 32 + l4 * 8];
#pragma unroll
        for (int ni = 0; ni < 4; ni++)
            bfr[ni] = *(const bf16x8*)&Bs[(wc + ni * 16 + l15) * 64 + kk * 32 + l4 * 8];
#pragma unroll
        for (int mi = 0; mi < 4; mi++)
#pragma unroll
            for (int ni = 0; ni < 4; ni++)
                acc[mi][ni] = mfma16(af[mi], bfr[ni], acc[mi][ni]);
    }
}

// ---------------- V transpose: v[b][s][d] -> vt[b][d][s] -------------------
__global__ __launch_bounds__(256) void vtrans(const u16* __restrict__ v,
                                              u16* __restrict__ vt) {
    __shared__ __align__(16) u16 t[64][80];
    const int s0 = blockIdx.x * 64, d0 = blockIdx.y * 64;
    const size_t bo = (size_t)blockIdx.z * SEQ * DOUT;
    const int tid = threadIdx.x;
#pragma unroll
    for (int i = 0; i < 2; i++) {
        int e = (tid + i * 256) * 8;
        int r = e >> 6, c = e & 63;
        *(uint4*)&t[r][c] = *(const uint4*)&v[bo + (size_t)(s0 + r) * DOUT + d0 + c];
    }
    __syncthreads();
#pragma unroll
    for (int i = 0; i < 2; i++) {
        int e = (tid + i * 256) * 8;
        int rd = e >> 6, cs = e & 63;
        u16 tmp[8];
#pragma unroll
        for (int j = 0; j < 8; j++) tmp[j] = t[cs + j][rd];
        uint4 o;
        o.x = (unsigned)tmp[0] | ((unsigned)tmp[1] << 16);
        o.y = (unsigned)tmp[2] | ((unsigned)tmp[3] << 16);
        o.z = (unsigned)tmp[4] | ((unsigned)tmp[5] << 16);
        o.w = (unsigned)tmp[6] | ((unsigned)tmp[7] << 16);
        *(uint4*)&vt[(size_t)blockIdx.z * DOUT * SEQ + (size_t)(d0 + rd) * SEQ + s0 + cs] = o;
    }
}

// ---------------- QK^T: S[b][q][k] (bf16, scaled+masked), causal skip ------
__global__ __launch_bounds__(256) void qk_gemm(const u16* __restrict__ qg,
                                               const u16* __restrict__ kg,
                                               u16* __restrict__ sg) {
    const int mt = blockIdx.x, nt = blockIdx.y, b = blockIdx.z;
    if (nt > mt) return;
    __shared__ __align__(16) u16 As[128 * 64];
    __shared__ __align__(16) u16 Bs[128 * 64];
    const size_t bo = (size_t)b * SEQ * DOUT;
    const size_t so = (size_t)b * SEQ * SEQ;
    const int tid = threadIdx.x, lane = tid & 63, wv = tid >> 6;
    const int wr = (wv >> 1) * 64, wc = (wv & 1) * 64;
    const int l15 = lane & 15, l4 = lane >> 4;
    const int m0 = mt * 128, n0 = nt * 128;
    f32x4 acc[4][4] = {};

    for (int k0 = 0; k0 < DIN; k0 += 64) {
        __syncthreads();
        stage_tile(qg + bo + (size_t)m0 * DOUT + k0, DOUT, As, tid);
        stage_tile(kg + bo + (size_t)n0 * DOUT + k0, DOUT, Bs, tid);
        __syncthreads();
        kstep(As, Bs, wr, wc, l15, l4, acc);
    }
#pragma unroll
    for (int mi = 0; mi < 4; mi++)
#pragma unroll
        for (int rr = 0; rr < 4; rr++) {
            int q = m0 + wr + mi * 16 + l4 * 4 + rr;
#pragma unroll
            for (int ni = 0; ni < 4; ni++) {
                int kcol = n0 + wc + ni * 16 + l15;
                u16 val = (kcol <= q) ? f2bf(acc[mi][ni][rr] * SCALE) : (u16)0xFF80;
                sg[so + (size_t)q * SEQ + kcol] = val;
            }
        }
}

// ---------------- row softmax in place: one wave per row -------------------
__global__ __launch_bounds__(256) void softmax_rows(u16* __restrict__ sg) {
    const int row = blockIdx.x * 4 + (threadIdx.x >> 6);
    const int lane = threadIdx.x & 63;
    const int b = row >> 11, q = row & 2047;
    u16* srow = sg + (size_t)b * SEQ * SEQ + (size_t)q * SEQ;
    const int kend = ((q >> 7) + 1) << 7;
    float v[4][8];
    float m = -__builtin_inff();
#pragma unroll
    for (int c = 0; c < 4; c++) {
        int k = c * 512 + lane * 8;
        if (k < kend) {
            uint4 x = *(const uint4*)&srow[k];
            unsigned w0 = x.x, w1 = x.y, w2 = x.z, w3 = x.w;
            v[c][0] = __uint_as_float(w0 << 16); v[c][1] = __uint_as_float(w0 & 0xffff0000u);
            v[c][2] = __uint_as_float(w1 << 16); v[c][3] = __uint_as_float(w1 & 0xffff0000u);
            v[c][4] = __uint_as_float(w2 << 16); v[c][5] = __uint_as_float(w2 & 0xffff0000u);
            v[c][6] = __uint_as_float(w3 << 16); v[c][7] = __uint_as_float(w3 & 0xffff0000u);
        } else {
#pragma unroll
            for (int j = 0; j < 8; j++) v[c][j] = -__builtin_inff();
        }
#pragma unroll
        for (int j = 0; j < 8; j++) m = fmaxf(m, v[c][j]);
    }
#pragma unroll
    for (int off = 32; off >= 1; off >>= 1) m = fmaxf(m, __shfl_xor(m, off));
    float s = 0.f;
#pragma unroll
    for (int c = 0; c < 4; c++)
#pragma unroll
        for (int j = 0; j < 8; j++) { v[c][j] = __expf(v[c][j] - m); s += v[c][j]; }
#pragma unroll
    for (int off = 32; off >= 1; off >>= 1) s += __shfl_xor(s, off);
    float inv = 1.f / s;
#pragma unroll
    for (int c = 0; c < 4; c++) {
        int k = c * 512 + lane * 8;
        if (k < kend) {
            uint4 o;
            o.x = (unsigned)f2bf(v[c][0] * inv) | ((unsigned)f2bf(v[c][1] * inv) << 16);
            o.y = (unsigned)f2bf(v[c][2] * inv) | ((unsigned)f2bf(v[c][3] * inv) << 16);
            o.z = (unsigned)f2bf(v[c][4] * inv) | ((unsigned)f2bf(v[c][5] * inv) << 16);
            o.w = (unsigned)f2bf(v[c][6] * inv) | ((unsigned)f2bf(v[c][7] * inv) << 16);
            *(uint4*)&srow[k] = o;
        }
    }
}

// ---------------- PV: O[b][q][d] = P * V, fp32 out, causal K-bound ---------
__global__ __launch_bounds__(256) void pv_gemm(const u16* __restrict__ pg,
                                               const u16* __restrict__ vtg,
                                               float* __restrict__ og) {
    __shared__ __align__(16) u16 As[128 * 64];
    __shared__ __align__(16) u16 Bs[128 * 64];
    const int mt = blockIdx.x, nt = blockIdx.y, b = blockIdx.z;
    const size_t so = (size_t)b * SEQ * SEQ;
    const size_t vo = (size_t)b * DOUT * SEQ;
    const size_t oo = (size_t)b * SEQ * DOUT;
    const int tid = threadIdx.x, lane = tid & 63, wv = tid >> 6;
    const int wr = (wv >> 1) * 64, wc = (wv & 1) * 64;
    const int l15 = lane & 15, l4 = lane >> 4;
    const int m0 = mt * 128, n0 = nt * 128;
    const int kend = (mt + 1) * 128;
    f32x4 acc[4][4] = {};

    for (int k0 = 0; k0 < kend; k0 += 64) {
        __syncthreads();
        stage_tile(pg + so + (size_t)m0 * SEQ + k0, SEQ, As, tid);
        stage_tile(vtg + vo + (size_t)n0 * SEQ + k0, SEQ, Bs, tid);
        __syncthreads();
        kstep(As, Bs, wr, wc, l15, l4, acc);
    }
#pragma unroll
    for (int mi = 0; mi < 4; mi++)
#pragma unroll
        for (int rr = 0; rr < 4; rr++) {
            int q = m0 + wr + mi * 16 + l4 * 4 + rr;
#pragma unroll
            for (int ni = 0; ni < 4; ni++) {
                int d = n0 + wc + ni * 16 + l15;
                og[oo + (size_t)q * DOUT + d] = acc[mi][ni][rr];
            }
        }
}

extern "C" void kernel_launch(void* const* d_in, const int* in_sizes, int n_in,
                              void* d_out, int out_size, void* d_ws, size_t ws_size,
                              hipStream_t stream) {
    const float* x  = (const float*)d_in[0];
    const float* wq = (const float*)d_in[1];
    const float* wk = (const float*)d_in[2];
    const float* wv = (const float*)d_in[3];
    float* out = (float*)d_out;

    const size_t NX  = (size_t)BATCH * SEQ * DIN;  // 8M elems
    const size_t NWT = (size_t)DOUT * DIN;         // 1M elems
    u16* xb  = (u16*)d_ws;            // 16 MB
    u16* wb  = xb + NX;               // 6 MB (wq|wk|wv = Wcat[3072][1024])
    u16* qkv = wb + 3 * NWT;          // 48 MB (q,k,v)
    u16* vt  = qkv + 3 * NX;          // 16 MB
    u16* sb  = vt + NX;               // 33.5 MB scores/probs (bf16, in-place)

    cvt_all<<<(NX + 3 * NWT) / 8 / 256, 256, 0, stream>>>(x, wq, wk, wv, xb);

    (void)hipFuncSetAttribute((const void*)qkv_gemm256,
                              hipFuncAttributeMaxDynamicSharedMemorySize, 131072);
    qkv_gemm256<<<dim3(256), dim3(512), 131072, stream>>>(xb, wb, qkv);

    vtrans<<<dim3(SEQ / 64, DOUT / 64, BATCH), 256, 0, stream>>>(qkv + 2 * NX, vt);

    qk_gemm<<<dim3(16, 16, 4), 256, 0, stream>>>(qkv, qkv + NX, sb);

    softmax_rows<<<(BATCH * SEQ) / 4, 256, 0, stream>>>(sb);

    pv_gemm<<<dim3(16, 8, 4), 256, 0, stream>>>(sb, vt, out);
}

// Round 7
// 183.324 us; speedup vs baseline: 1.2577x; 1.0603x over previous
//
#include <hip/hip_runtime.h>
#include <hip/hip_bf16.h>
#include <cstdint>

#define BATCH 4
#define SEQ   2048
#define DIN   1024
#define DOUT  1024
#define SCALE 0.03125f   // 1/sqrt(1024)

typedef unsigned short u16;
typedef float  f32x4  __attribute__((ext_vector_type(4)));
typedef __bf16 bf16x8 __attribute__((ext_vector_type(8)));

__device__ __forceinline__ u16 f2bf(float f) {
    unsigned u = __float_as_uint(f);
    unsigned r = 0x7fffu + ((u >> 16) & 1u);
    return (u16)((u + r) >> 16);
}

__device__ __forceinline__ f32x4 mfma16(bf16x8 a, bf16x8 b, f32x4 c) {
    return __builtin_amdgcn_mfma_f32_16x16x32_bf16(a, b, c, 0, 0, 0);
}

__device__ __forceinline__ void gl_lds16(const u16* g, u16* l) {
    __builtin_amdgcn_global_load_lds(
        (const __attribute__((address_space(1))) unsigned int*)g,
        (__attribute__((address_space(3))) unsigned int*)l, 16, 0, 0);
}

#define BAR    asm volatile("s_barrier" ::: "memory")
#define VMCNT4 asm volatile("s_waitcnt vmcnt(4)" ::: "memory")
#define VMCNT6 asm volatile("s_waitcnt vmcnt(6)" ::: "memory")
#define VMCNT0 asm volatile("s_waitcnt vmcnt(0)" ::: "memory")
#define LGKM0  asm volatile("s_waitcnt lgkmcnt(0)" ::: "memory")

// ---------------- fused fp32 -> bf16 conversion (x | wq | wk | wv) ---------
__global__ __launch_bounds__(256) void cvt_all(const float* __restrict__ x,
                                               const float* __restrict__ wq,
                                               const float* __restrict__ wk,
                                               const float* __restrict__ wv,
                                               u16* __restrict__ dst) {
    const size_t NX = (size_t)BATCH * SEQ * DIN;
    size_t e = ((size_t)blockIdx.x * 256 + threadIdx.x) * 8;
    const float* src;
    size_t off;
    if (e < NX) { src = x; off = e; }
    else {
        size_t r = e - NX;
        int w = (int)(r >> 20);
        src = (w == 0) ? wq : (w == 1) ? wk : wv;
        off = r & ((1u << 20) - 1);
    }
    f32x4 a = *(const f32x4*)(src + off);
    f32x4 b = *(const f32x4*)(src + off + 4);
    uint4 o;
    o.x = (unsigned)f2bf(a[0]) | ((unsigned)f2bf(a[1]) << 16);
    o.y = (unsigned)f2bf(a[2]) | ((unsigned)f2bf(a[3]) << 16);
    o.z = (unsigned)f2bf(b[0]) | ((unsigned)f2bf(b[1]) << 16);
    o.w = (unsigned)f2bf(b[2]) | ((unsigned)f2bf(b[3]) << 16);
    *(uint4*)(dst + e) = o;
}

// ======================================================================
// Staging: 128-row x 64-col bf16 unit (16KB), linear rows, row-XOR
// swizzle (byte ^= (row&7)<<4) applied inverse on the global source.
// ======================================================================
__device__ __forceinline__ void stg128(const u16* __restrict__ g, int ld,
                                       u16* unit, int tid) {
#pragma unroll
    for (int i = 0; i < 2; i++) {
        int D = (i * 512 + tid) * 16;
        int r = D >> 7, w = D & 127;
        int gcol = (w ^ ((r & 7) << 4)) >> 1;
        gl_lds16(g + (size_t)r * ld + gcol, unit + (i * 512 + (tid >> 6) * 64) * 8);
    }
}

__device__ __forceinline__ void rd4(const u16* unit, int rowbase, int l15, int l4,
                                    bf16x8 f[4][2]) {
    const char* u = (const char*)unit;
#pragma unroll
    for (int i = 0; i < 4; i++) {
        int row = rowbase + i * 16 + l15;
#pragma unroll
        for (int kk = 0; kk < 2; kk++)
            f[i][kk] = *(const bf16x8*)(u + row * 128 +
                                        ((kk * 64 + l4 * 16) ^ ((row & 7) << 4)));
    }
}

__device__ __forceinline__ void rd2(const u16* unit, int rowbase, int l15, int l4,
                                    bf16x8 f[2][2]) {
    const char* u = (const char*)unit;
#pragma unroll
    for (int i = 0; i < 2; i++) {
        int row = rowbase + i * 16 + l15;
#pragma unroll
        for (int kk = 0; kk < 2; kk++)
            f[i][kk] = *(const bf16x8*)(u + row * 128 +
                                        ((kk * 64 + l4 * 16) ^ ((row & 7) << 4)));
    }
}

// ======================================================================
// 128x256-tile GEMM body, BK=64, 8 waves (2M x 4N), per-wave 64x64.
// SWAPPED mfma (W/V fragment as A-operand) -> thread holds 4 consecutive
// output cols -> vectorized stores. LDS 96KB = 2buf x {A,Bl,Bu} 16KB.
// ph1: ALL ds_reads (A + both B halves) | BAR | MFMA half1 | lgkm0 | BAR
// ph2: stage tile t+2 {A,Bl,Bu} | vmcnt(6) | BAR | MFMA half2 | BAR
// (2-phase staging lead; regions staged in ph2 are free: A read-complete
//  after ph1, B read-complete after ph1's lgkm0+BAR.)
// ======================================================================
#define G128_PH1(AC, BC)                                                         \
    rd4((AC), wm * 64, l15, l4, a);                                              \
    rd2((BC) + (wn >> 1) * 8192, browb, l15, l4, b01);                           \
    rd2((BC) + (wn >> 1) * 8192, browb + 32, l15, l4, b23);                      \
    BAR;                                                                         \
    __builtin_amdgcn_s_setprio(1);                                               \
    _Pragma("unroll") for (int kk = 0; kk < 2; kk++)                             \
    _Pragma("unroll") for (int mi = 0; mi < 4; mi++)                             \
    _Pragma("unroll") for (int j = 0; j < 2; j++)                                \
        acc[mi][j] = mfma16(b01[j][kk], a[mi][kk], acc[mi][j]);                  \
    __builtin_amdgcn_s_setprio(0);                                               \
    LGKM0;                                                                       \
    BAR;

#define G128_PH2(CURB, K2)                                                       \
    stg128(Ag_ + (K2), LDA_, lds + (CURB), tid);                                 \
    stg128(Bg_ + (K2), LDB_, lds + (CURB) + 8192, tid);                          \
    stg128(Bg_ + (size_t)128 * LDB_ + (K2), LDB_, lds + (CURB) + 16384, tid);    \
    VMCNT6; BAR;                                                                 \
    __builtin_amdgcn_s_setprio(1);                                               \
    _Pragma("unroll") for (int kk = 0; kk < 2; kk++)                             \
    _Pragma("unroll") for (int mi = 0; mi < 4; mi++)                             \
    _Pragma("unroll") for (int j = 0; j < 2; j++)                                \
        acc[mi][2 + j] = mfma16(b23[j][kk], a[mi][kk], acc[mi][2 + j]);          \
    __builtin_amdgcn_s_setprio(0);                                               \
    BAR;

#define G128_BODY(Ag, LDA, Bg, LDB, NKT)                                         \
    f32x4 acc[4][4] = {};                                                        \
    bf16x8 a[4][2], b01[2][2], b23[2][2];                                        \
    const u16* Ag_ = (Ag); const u16* Bg_ = (Bg);                                \
    const int LDA_ = (LDA), LDB_ = (LDB), NKT_ = (NKT);                          \
    const int browb = (wn & 1) * 64;                                             \
    stg128(Ag_, LDA_, lds, tid);                                                 \
    stg128(Bg_, LDB_, lds + 8192, tid);                                          \
    stg128(Bg_ + (size_t)128 * LDB_, LDB_, lds + 16384, tid);                    \
    stg128(Ag_ + 64, LDA_, lds + 24576, tid);                                    \
    stg128(Bg_ + 64, LDB_, lds + 24576 + 8192, tid);                             \
    stg128(Bg_ + (size_t)128 * LDB_ + 64, LDB_, lds + 24576 + 16384, tid);       \
    VMCNT6; BAR;                                                                 \
    for (int t = 0; t < NKT_; t += 2) {                                          \
        {                                                                        \
            const int k2 = ((t + 2 < NKT_) ? t + 2 : NKT_ - 1) * 64;             \
            G128_PH1(lds, lds + 8192)                                            \
            G128_PH2(0, k2)                                                      \
        }                                                                        \
        {                                                                        \
            const int k2 = ((t + 3 < NKT_) ? t + 3 : NKT_ - 1) * 64;             \
            G128_PH1(lds + 24576, lds + 24576 + 8192)                            \
            G128_PH2(24576, k2)                                                  \
        }                                                                        \
    }                                                                            \
    VMCNT0;

// ======================================================================
// QKV: C[8192,3072] = X * Wcat^T  (256x256, 8-phase, persistent 256 blk)
// round-5-proven schedule + swapped mfma, vectorized stores, XCD tile map
// ======================================================================
__device__ __forceinline__ void stg_half(const u16* __restrict__ gbase,
                                         u16* unit, int tid) {
#pragma unroll
    for (int i = 0; i < 2; i++) {
        int D = (i * 512 + tid) * 16;
        int r = D >> 7, w = D & 127;
        int gcol = (w ^ ((r & 7) << 4)) >> 1;
        gl_lds16(gbase + (size_t)r * DIN + gcol,
                 unit + (i * 512 + (tid >> 6) * 64) * 8);
    }
}

__device__ __forceinline__ void rdA8(const u16* unit, int mh, int l15, int l4,
                                     int sw, bf16x8 a[4][2]) {
    const char* u = (const char*)unit;
#pragma unroll
    for (int mi = 0; mi < 4; mi++)
#pragma unroll
        for (int kk = 0; kk < 2; kk++)
            a[mi][kk] = *(const bf16x8*)(u + (mh * 64 + mi * 16 + l15) * 128 +
                                         ((kk * 64 + l4 * 16) ^ sw));
}

__device__ __forceinline__ void rdB8(const u16* unit, int wn1, int nh, int l15,
                                     int l4, int sw, bf16x8 b[2][2]) {
    const char* u = (const char*)unit;
#pragma unroll
    for (int ni = 0; ni < 2; ni++)
#pragma unroll
        for (int kk = 0; kk < 2; kk++)
            b[ni][kk] = *(const bf16x8*)(u + (wn1 * 64 + nh * 32 + ni * 16 + l15) * 128 +
                                         ((kk * 64 + l4 * 16) ^ sw));
}

#define QUAD(MH, NH)                                                         \
    __builtin_amdgcn_s_setprio(1);                                           \
    _Pragma("unroll") for (int kk = 0; kk < 2; kk++)                         \
    _Pragma("unroll") for (int mi = 0; mi < 4; mi++)                         \
    _Pragma("unroll") for (int ni = 0; ni < 2; ni++)                         \
        acc[(MH)*4 + mi][(NH)*2 + ni] =                                      \
            mfma16(bb[NH][ni][kk], a[mi][kk], acc[(MH)*4 + mi][(NH)*2 + ni]);\
    __builtin_amdgcn_s_setprio(0);

__global__ __launch_bounds__(512) void qkv_gemm256(const u16* __restrict__ xb,
                                                   const u16* __restrict__ wb,
                                                   u16* __restrict__ qkv) {
    extern __shared__ __align__(16) u16 lds[];
    const int tid = threadIdx.x, lane = tid & 63, wid = tid >> 6;
    const int wm = wid >> 2, wn = wid & 3, bh = wn >> 1, wn1 = wn & 1;
    const int l15 = lane & 15, l4 = lane >> 4;
    const int sw = (l15 & 7) << 4;

    u16* A00 = lds;              u16* A01 = lds + 8192;
    u16* A10 = lds + 16384;      u16* A11 = lds + 24576;
    u16* B00 = lds + 32768;      u16* B01 = lds + 40960;
    u16* B10 = lds + 49152;      u16* B11 = lds + 57344;
    u16* Ar0 = lds + wm * 8192;
    u16* Ar1 = lds + 16384 + wm * 8192;
    u16* Br0 = lds + 32768 + bh * 8192;
    u16* Br1 = lds + 49152 + bh * 8192;

    for (int tile = blockIdx.x; tile < 384; tile += 256) {
        const int xcd = tile & 7, li = tile >> 3;        // li 0..47
        const int mt = xcd * 4 + li / 12, nt = li % 12;  // X panel L2-resident/XCD
        const int m0 = mt * 256, n0 = nt * 256;
        const u16* Ag = xb + (size_t)m0 * DIN;
        const u16* Bg = wb + (size_t)n0 * DIN;
        f32x4 acc[8][4] = {};
        bf16x8 a[4][2], bb[2][2][2];

        stg_half(Bg,                          B00, tid);
        stg_half(Bg + (size_t)128 * DIN,      B01, tid);
        stg_half(Ag,                          A00, tid);
        stg_half(Ag + (size_t)128 * DIN,      A01, tid);
        stg_half(Bg + 64,                     B10, tid);
        stg_half(Bg + (size_t)128 * DIN + 64, B11, tid);
        VMCNT4; BAR;

        for (int i = 0; i < 8; i++) {
            const int t1k = (2 * i + 1) * 64;
            const int k2 = ((2 * i + 2 < 16) ? 2 * i + 2 : 15) * 64;
            const int k3 = ((2 * i + 3 < 16) ? 2 * i + 3 : 15) * 64;
            rdA8(Ar0, 0, l15, l4, sw, a);
            rdB8(Br0, wn1, 0, l15, l4, sw, bb[0]);
            stg_half(Ag + t1k, A10, tid);
            BAR; QUAD(0, 0); BAR;
            rdB8(Br0, wn1, 1, l15, l4, sw, bb[1]);
            stg_half(Ag + (size_t)128 * DIN + t1k, A11, tid);
            BAR; QUAD(0, 1); BAR;
            rdA8(Ar0, 1, l15, l4, sw, a);
            stg_half(Bg + k2, B00, tid);
            BAR; QUAD(1, 0); BAR;
            stg_half(Bg + (size_t)128 * DIN + k2, B01, tid);
            VMCNT4; BAR; QUAD(1, 1); BAR;
            rdA8(Ar1, 0, l15, l4, sw, a);
            rdB8(Br1, wn1, 0, l15, l4, sw, bb[0]);
            stg_half(Ag + k2, A00, tid);
            BAR; QUAD(0, 0); BAR;
            rdB8(Br1, wn1, 1, l15, l4, sw, bb[1]);
            stg_half(Ag + (size_t)128 * DIN + k2, A01, tid);
            BAR; QUAD(0, 1); BAR;
            rdA8(Ar1, 1, l15, l4, sw, a);
            stg_half(Bg + k3, B10, tid);
            BAR; QUAD(1, 0); BAR;
            stg_half(Bg + (size_t)128 * DIN + k3, B11, tid);
            VMCNT4; BAR; QUAD(1, 1); BAR;
        }
        VMCNT0;

        const int wsel = n0 >> 10, c0 = n0 & 1023;
        u16* Op = qkv + (size_t)wsel * ((size_t)BATCH * SEQ * DOUT);
#pragma unroll
        for (int ai = 0; ai < 8; ai++) {
            int row = m0 + wm * 128 + ai * 16 + l15;
#pragma unroll
            for (int bj = 0; bj < 4; bj++) {
                int col = c0 + wn * 64 + bj * 16 + l4 * 4;
                uint2 o;
                o.x = (unsigned)f2bf(acc[ai][bj][0]) | ((unsigned)f2bf(acc[ai][bj][1]) << 16);
                o.y = (unsigned)f2bf(acc[ai][bj][2]) | ((unsigned)f2bf(acc[ai][bj][3]) << 16);
                *(uint2*)&Op[(size_t)row * DOUT + col] = o;
            }
        }
    }
}

// ---------------- V transpose: v[b][s][d] -> vt[b][d][s] -------------------
__global__ __launch_bounds__(256) void vtrans(const u16* __restrict__ v,
                                              u16* __restrict__ vt) {
    __shared__ __align__(16) u16 t[64][80];
    const int s0 = blockIdx.x * 64, d0 = blockIdx.y * 64;
    const size_t bo = (size_t)blockIdx.z * SEQ * DOUT;
    const int tid = threadIdx.x;
#pragma unroll
    for (int i = 0; i < 2; i++) {
        int e = (tid + i * 256) * 8;
        int r = e >> 6, c = e & 63;
        *(uint4*)&t[r][c] = *(const uint4*)&v[bo + (size_t)(s0 + r) * DOUT + d0 + c];
    }
    __syncthreads();
#pragma unroll
    for (int i = 0; i < 2; i++) {
        int e = (tid + i * 256) * 8;
        int rd = e >> 6, cs = e & 63;
        u16 tmp[8];
#pragma unroll
        for (int j = 0; j < 8; j++) tmp[j] = t[cs + j][rd];
        uint4 o;
        o.x = (unsigned)tmp[0] | ((unsigned)tmp[1] << 16);
        o.y = (unsigned)tmp[2] | ((unsigned)tmp[3] << 16);
        o.z = (unsigned)tmp[4] | ((unsigned)tmp[5] << 16);
        o.w = (unsigned)tmp[6] | ((unsigned)tmp[7] << 16);
        *(uint4*)&vt[(size_t)blockIdx.z * DOUT * SEQ + (size_t)(d0 + rd) * SEQ + s0 + cs] = o;
    }
}

// ---------------- QK^T (128x256 2-phase, triangular grid) ------------------
__global__ __launch_bounds__(512) void qk3(const u16* __restrict__ qg,
                                           const u16* __restrict__ kg,
                                           u16* __restrict__ sg) {
    extern __shared__ __align__(16) u16 lds[];
    const int bxx = blockIdx.x, batch = blockIdx.y;
    int mt = 0, base = 0;
#pragma unroll 16
    for (int m = 0; m < 16; m++) {
        int c = (m >> 1) + 1;
        if (bxx < base + c) { mt = m; break; }
        base += c;
    }
    const int nt = bxx - base;
    const int m0 = mt * 128, n0 = nt * 256;
    const int tid = threadIdx.x, lane = tid & 63;
    const int wm = (tid >> 6) >> 2, wn = (tid >> 6) & 3;
    const int l15 = lane & 15, l4 = lane >> 4;
    const size_t bo = (size_t)batch * SEQ * DOUT;
    const u16* Aq = qg + bo + (size_t)m0 * DOUT;
    const u16* Bk = kg + bo + (size_t)n0 * DOUT;

    G128_BODY(Aq, DOUT, Bk, DOUT, 16)

    u16* Sp = sg + (size_t)batch * SEQ * SEQ;
#pragma unroll
    for (int ai = 0; ai < 4; ai++) {
        int q = m0 + wm * 64 + ai * 16 + l15;
#pragma unroll
        for (int bj = 0; bj < 4; bj++) {
            int kc = n0 + wn * 64 + bj * 16 + l4 * 4;
            u16 v0 = (kc + 0 <= q) ? f2bf(acc[ai][bj][0] * SCALE) : (u16)0xFF80;
            u16 v1 = (kc + 1 <= q) ? f2bf(acc[ai][bj][1] * SCALE) : (u16)0xFF80;
            u16 v2 = (kc + 2 <= q) ? f2bf(acc[ai][bj][2] * SCALE) : (u16)0xFF80;
            u16 v3 = (kc + 3 <= q) ? f2bf(acc[ai][bj][3] * SCALE) : (u16)0xFF80;
            uint2 o;
            o.x = (unsigned)v0 | ((unsigned)v1 << 16);
            o.y = (unsigned)v2 | ((unsigned)v3 << 16);
            *(uint2*)&Sp[(size_t)q * SEQ + kc] = o;
        }
    }
}

// ---------------- PV (128x256 2-phase, causal nkt, 256 blocks) -------------
__global__ __launch_bounds__(512) void pv3(const u16* __restrict__ pg,
                                           const u16* __restrict__ vtg,
                                           float* __restrict__ og) {
    extern __shared__ __align__(16) u16 lds[];
    const int mt = blockIdx.x, batch = blockIdx.z;
    const int m0 = mt * 128, n0 = blockIdx.y * 256;
    const int nkt = (mt + 1) * 2;
    const int tid = threadIdx.x, lane = tid & 63;
    const int wm = (tid >> 6) >> 2, wn = (tid >> 6) & 3;
    const int l15 = lane & 15, l4 = lane >> 4;
    const u16* Ap = pg + (size_t)batch * SEQ * SEQ + (size_t)m0 * SEQ;
    const u16* Bv = vtg + (size_t)batch * DOUT * SEQ + (size_t)n0 * SEQ;

    G128_BODY(Ap, SEQ, Bv, SEQ, nkt)

    float* Oq = og + (size_t)batch * SEQ * DOUT;
#pragma unroll
    for (int ai = 0; ai < 4; ai++) {
        int q = m0 + wm * 64 + ai * 16 + l15;
#pragma unroll
        for (int bj = 0; bj < 4; bj++) {
            int d = n0 + wn * 64 + bj * 16 + l4 * 4;
            *(f32x4*)&Oq[(size_t)q * DOUT + d] = acc[ai][bj];
        }
    }
}

// ---------------- row softmax in place: one wave per row -------------------
__global__ __launch_bounds__(256) void softmax_rows(u16* __restrict__ sg) {
    const int row = blockIdx.x * 4 + (threadIdx.x >> 6);
    const int lane = threadIdx.x & 63;
    const int b = row >> 11, q = row & 2047;
    u16* srow = sg + (size_t)b * SEQ * SEQ + (size_t)q * SEQ;
    const int kend = ((q >> 7) + 1) << 7;
    float v[4][8];
    float m = -__builtin_inff();
#pragma unroll
    for (int c = 0; c < 4; c++) {
        int k = c * 512 + lane * 8;
        if (k < kend) {
            uint4 x = *(const uint4*)&srow[k];
            unsigned w0 = x.x, w1 = x.y, w2 = x.z, w3 = x.w;
            v[c][0] = __uint_as_float(w0 << 16); v[c][1] = __uint_as_float(w0 & 0xffff0000u);
            v[c][2] = __uint_as_float(w1 << 16); v[c][3] = __uint_as_float(w1 & 0xffff0000u);
            v[c][4] = __uint_as_float(w2 << 16); v[c][5] = __uint_as_float(w2 & 0xffff0000u);
            v[c][6] = __uint_as_float(w3 << 16); v[c][7] = __uint_as_float(w3 & 0xffff0000u);
        } else {
#pragma unroll
            for (int j = 0; j < 8; j++) v[c][j] = -__builtin_inff();
        }
#pragma unroll
        for (int j = 0; j < 8; j++) m = fmaxf(m, v[c][j]);
    }
#pragma unroll
    for (int off = 32; off >= 1; off >>= 1) m = fmaxf(m, __shfl_xor(m, off));
    float s = 0.f;
#pragma unroll
    for (int c = 0; c < 4; c++)
#pragma unroll
        for (int j = 0; j < 8; j++) { v[c][j] = __expf(v[c][j] - m); s += v[c][j]; }
#pragma unroll
    for (int off = 32; off >= 1; off >>= 1) s += __shfl_xor(s, off);
    float inv = 1.f / s;
#pragma unroll
    for (int c = 0; c < 4; c++) {
        int k = c * 512 + lane * 8;
        if (k < kend) {
            uint4 o;
            o.x = (unsigned)f2bf(v[c][0] * inv) | ((unsigned)f2bf(v[c][1] * inv) << 16);
            o.y = (unsigned)f2bf(v[c][2] * inv) | ((unsigned)f2bf(v[c][3] * inv) << 16);
            o.z = (unsigned)f2bf(v[c][4] * inv) | ((unsigned)f2bf(v[c][5] * inv) << 16);
            o.w = (unsigned)f2bf(v[c][6] * inv) | ((unsigned)f2bf(v[c][7] * inv) << 16);
            *(uint4*)&srow[k] = o;
        }
    }
}

extern "C" void kernel_launch(void* const* d_in, const int* in_sizes, int n_in,
                              void* d_out, int out_size, void* d_ws, size_t ws_size,
                              hipStream_t stream) {
    const float* x  = (const float*)d_in[0];
    const float* wq = (const float*)d_in[1];
    const float* wk = (const float*)d_in[2];
    const float* wv = (const float*)d_in[3];
    float* out = (float*)d_out;

    const size_t NX  = (size_t)BATCH * SEQ * DIN;  // 8M elems
    const size_t NWT = (size_t)DOUT * DIN;         // 1M elems
    u16* xb  = (u16*)d_ws;            // 16 MB
    u16* wb  = xb + NX;               // 6 MB (wq|wk|wv = Wcat[3072][1024])
    u16* qkv = wb + 3 * NWT;          // 48 MB (q,k,v)
    u16* vt  = qkv + 3 * NX;          // 16 MB
    u16* sb  = vt + NX;               // 33.5 MB scores/probs (bf16, in-place)

    cvt_all<<<(NX + 3 * NWT) / 8 / 256, 256, 0, stream>>>(x, wq, wk, wv, xb);

    (void)hipFuncSetAttribute((const void*)qkv_gemm256,
                              hipFuncAttributeMaxDynamicSharedMemorySize, 131072);
    (void)hipFuncSetAttribute((const void*)qk3,
                              hipFuncAttributeMaxDynamicSharedMemorySize, 98304);
    (void)hipFuncSetAttribute((const void*)pv3,
                              hipFuncAttributeMaxDynamicSharedMemorySize, 98304);

    qkv_gemm256<<<dim3(256), dim3(512), 131072, stream>>>(xb, wb, qkv);

    vtrans<<<dim3(SEQ / 64, DOUT / 64, BATCH), 256, 0, stream>>>(qkv + 2 * NX, vt);

    qk3<<<dim3(72, BATCH), dim3(512), 98304, stream>>>(qkv, qkv + NX, sb);

    softmax_rows<<<(BATCH * SEQ) / 4, 256, 0, stream>>>(sb);

    pv3<<<dim3(16, 4, 4), dim3(512), 98304, stream>>>(sb, vt, out);
}